// Round 10
// baseline (288.147 us; speedup 1.0000x reference)
//
#include <hip/hip_runtime.h>
#include <stdint.h>

// ---------------------------------------------------------------------------
// RandomizedBertSelfAttention: fused QKV projection + flash attention.
// R19 = R18 with the replay-safe flag protocol. R18's combine was CORRECT
// on the first launch (absmax 4.88e-4 -- fences/atomics across XCDs work)
// but failed the post-timing tripwire: graph replays don't re-memset
// d_out, so the in-output flag cell never re-armed. Fix: 384 u32 flags in
// DEAD workspace (wqh region, after Lp), re-zeroed EVERY launch by a
// captured hipMemsetAsync enqueued between qkv and attn (stream-ordered;
// bytes are dead wqh by then). sp0 writes its full f32 tile (no stash).
// Protocol: partials -> __syncthreads -> t0 {release fence; atomicAdd} ->
// LDS broadcast -> old==1: acquire fence, combine partner+registers.
// Removes reduce_k (~7us work + ~10us boundary) for a ~2us memset.
// ---------------------------------------------------------------------------

typedef float    f32x4 __attribute__((ext_vector_type(4)));
typedef _Float16 h16x8 __attribute__((ext_vector_type(8)));
typedef _Float16 h16x4 __attribute__((ext_vector_type(4)));
typedef _Float16 h16x2 __attribute__((ext_vector_type(2)));
typedef __fp16   fp16x2 __attribute__((ext_vector_type(2)));
typedef unsigned short u16;

#define MFMA32(A, B, C) __builtin_amdgcn_mfma_f32_16x16x32_f16((A), (B), (C), 0, 0, 0)
#define ZERO4 ((f32x4){0.f, 0.f, 0.f, 0.f})

#define SEQ 4096
#define HID 768
#define NH  12
#define DH  64

#define CEXP 0.18033688011112042f   // log2(e)/sqrt(64), folded into Q

#define WAITV(N) asm volatile("s_waitcnt vmcnt(" #N ")" ::: "memory")
#define SBAR()   __builtin_amdgcn_s_barrier()
#define SCHED0() __builtin_amdgcn_sched_barrier(0)

__device__ __forceinline__ u16 f2h(float f) {
  union { _Float16 h; u16 u; } v;
  v.h = (_Float16)f;
  return v.u;
}
__device__ __forceinline__ float h2f(u16 u) {
  union { u16 u; _Float16 h; } v;
  v.u = u;
  return (float)v.h;
}

__device__ __forceinline__ void gload_lds16(const void* g, void* l) {
  __builtin_amdgcn_global_load_lds(
      (__attribute__((address_space(1))) void*)(g),
      (__attribute__((address_space(3))) void*)(l),
      16, 0, 0);
}

// ---------------------------------------------------------------------------
// Kernel 1: cast x, Wq, Wk, Wv to fp16
// ---------------------------------------------------------------------------
__global__ __launch_bounds__(256) void cast_all_k(
    const float* __restrict__ x,  const float* __restrict__ wq,
    const float* __restrict__ wk, const float* __restrict__ wv,
    u16* __restrict__ xh,  u16* __restrict__ wqh,
    u16* __restrict__ wkh, u16* __restrict__ wvh)
{
  int i = blockIdx.x * 256 + threadIdx.x;
  const int NX4 = (SEQ * HID) / 4;
  const int NW4 = (HID * HID) / 4;
  const float4* src; ushort4* dst; int idx;
  if (i < NX4) {
    src = (const float4*)x; dst = (ushort4*)xh; idx = i;
  } else {
    int j = i - NX4;
    int w = j / NW4;
    idx = j - w * NW4;
    src = (const float4*)(w == 0 ? wq : (w == 1 ? wk : wv));
    dst = (ushort4*)(w == 0 ? wqh : (w == 1 ? wkh : wvh));
  }
  float4 v = src[idx];
  ushort4 o;
  o.x = f2h(v.x); o.y = f2h(v.y); o.z = f2h(v.z); o.w = f2h(v.w);
  dst[idx] = o;
}

// ---------------------------------------------------------------------------
// Kernel 2: QKV projection GEMM, C = x @ W^T + b. 128x128 tile, BK=64,
// XOR-swizzled LDS staging (conflict-free frags), launch_bounds(256,3).
// z==0 (Q): pre-scaled by CEXP. z==2 (V): stored transposed Vt[hid][s] with
// the PV permutation pi per 32-kv group. Epilogue: acc -> swizzled LDS ->
// b128 row reads -> coalesced dwordx4 global stores. (R9/R14-proven.)
// ---------------------------------------------------------------------------
__global__ __launch_bounds__(256, 3) void qkv_gemm_k(
    const u16* __restrict__ xh,
    const u16* __restrict__ wqh, const u16* __restrict__ wkh, const u16* __restrict__ wvh,
    const float* __restrict__ bq, const float* __restrict__ bk, const float* __restrict__ bv,
    u16* __restrict__ Qh, u16* __restrict__ Kh, u16* __restrict__ Vt)
{
  __shared__ u16 S[128 * 128];   // 32 KB: K-loop: A=[0,8192), B=[8192,16384) u16
                                 // epilogue: Cs[128][128] (swizzled chunks)

  const int t = threadIdx.x;
  const int wave = t >> 6, lane = t & 63;
  const int m = lane & 15, quad = lane >> 4;
  const int z  = blockIdx.z;
  const int n0 = blockIdx.x * 128;
  const int m0 = blockIdx.y * 128;

  const u16*   W    = (z == 0) ? wqh : (z == 1) ? wkh : wvh;
  const float* bias = (z == 0) ? bq  : (z == 1) ? bk  : bv;

  const int wm = (wave >> 1) * 64;
  const int wn = (wave & 1) * 64;

  f32x4 acc[4][4];
#pragma unroll
  for (int i = 0; i < 4; i++)
#pragma unroll
    for (int j = 0; j < 4; j++) acc[i][j] = ZERO4;

  // staging: call c covers rows c*32 + wave*8 + (lane>>3), chunk lane&7,
  // global-side swizzle ^(row&7); LDS dest contiguous (wave base + lane*16)
  const int srow = wave * 8 + (lane >> 3);
  const int scg  = (lane & 7) ^ (srow & 7);
  const u16* gA = xh + (m0 + srow) * HID + scg * 8;
  const u16* gB = W  + (n0 + srow) * HID + scg * 8;
  u16* lA = S + wave * 512;
  u16* lB = S + 8192 + wave * 512;

  for (int k0 = 0; k0 < HID; k0 += 64) {
    __syncthreads();
#pragma unroll
    for (int c = 0; c < 4; c++) {
      gload_lds16(gA + c * 32 * HID + k0, lA + c * 2048);
      gload_lds16(gB + c * 32 * HID + k0, lB + c * 2048);
    }
    __syncthreads();

#pragma unroll
    for (int s = 0; s < 2; s++) {
      h16x8 af[4], bf[4];
#pragma unroll
      for (int i = 0; i < 4; i++)
        af[i] = *(const h16x8*)(S + (wm + i * 16 + m) * 64
                                + ((s * 4 + quad) ^ (m & 7)) * 8);
#pragma unroll
      for (int j = 0; j < 4; j++)
        bf[j] = *(const h16x8*)(S + 8192 + (wn + j * 16 + m) * 64
                                + ((s * 4 + quad) ^ (m & 7)) * 8);
#pragma unroll
      for (int i = 0; i < 4; i++)
#pragma unroll
        for (int j = 0; j < 4; j++)
          acc[i][j] = MFMA32(af[i], bf[j], acc[i][j]);
    }
  }

  __syncthreads();   // all frag reads done — S becomes the epilogue tile Cs

  // C/D layout: col = lane&15 (within 16-tile), row = quad*4 + reg
  if (z < 2) {
    // Cs[s][col'] u16, chunk (col'>>3) stored at slot ^(s&15)
    const float sc = (z == 0) ? CEXP : 1.0f;
#pragma unroll
    for (int i = 0; i < 4; i++) {
      int sl = wm + i * 16 + quad * 4;            // local s, +r
#pragma unroll
      for (int j = 0; j < 4; j++) {
        int colp = wn + j * 16 + m;               // local col
        float bb = bias[n0 + colp];
        int c = colp >> 3, sub = colp & 7;
#pragma unroll
        for (int r = 0; r < 4; r++)
          S[(sl + r) * 128 + ((c ^ ((sl + r) & 15)) * 8) + sub] =
              f2h((acc[i][j][r] + bb) * sc);
      }
    }
    __syncthreads();
    u16* outp = (z == 0) ? Qh : Kh;
    const int ch = t & 15;                        // global chunk this thread reads
#pragma unroll
    for (int rr = 0; rr < 8; rr++) {
      int s = rr * 16 + (t >> 4);
      h16x8 v = *(const h16x8*)(S + s * 128 + ((ch ^ (s & 15)) * 8));
      *(h16x8*)(outp + (m0 + s) * HID + n0 + ch * 8) = v;
    }
  } else {
    // Cs[n][s'] u16 with pi-permuted s' (per 32-group); b64 writes (4-phase floor)
#pragma unroll
    for (int i = 0; i < 4; i++) {
      int sl = wm + i * 16 + quad * 4;            // local s, multiple of 4
      int vp = (sl & ~31) + ((sl >> 2) & 3) * 8 + ((sl >> 4) & 1) * 4;
#pragma unroll
      for (int j = 0; j < 4; j++) {
        int nl = wn + j * 16 + m;                 // local hid
        float bb = bias[n0 + nl];
        h16x4 o4;
        o4[0] = (_Float16)(acc[i][j][0] + bb);
        o4[1] = (_Float16)(acc[i][j][1] + bb);
        o4[2] = (_Float16)(acc[i][j][2] + bb);
        o4[3] = (_Float16)(acc[i][j][3] + bb);
        *(h16x4*)(S + nl * 128 + (((vp >> 3) ^ (nl & 15)) * 8) + (vp & 7)) = o4;
      }
    }
    __syncthreads();
    const int ch = t & 15;
#pragma unroll
    for (int rr = 0; rr < 8; rr++) {
      int n = rr * 16 + (t >> 4);
      h16x8 v = *(const h16x8*)(S + n * 128 + ((ch ^ (n & 15)) * 8));
      *(h16x8*)(Vt + (n0 + n) * SEQ + m0 + ch * 8) = v;
    }
  }
}

// ---------------------------------------------------------------------------
// Kernel 3: flash attention, split-KV x2 (R11 structure + T1 XCD swizzle)
// + replay-safe fused combine. Block = 256 threads (4 waves), 32 q-rows/
// wave. QK^T swapped (A=K, B=Q). KVBLK=64, 3-ring Ks/Vs (48KB), single
// barrier per tile. Row-sums via ones-MFMA into Lacc. Grid 768 = 3/CU.
// ---------------------------------------------------------------------------

__device__ __forceinline__ void stage_kv(const u16* gKb, const u16* gVb,
                                         u16* lK, u16* lV, int kv0)
{
#pragma unroll
  for (int c = 0; c < 2; c++) {
    gload_lds16(gKb + (kv0 + c * 32) * HID, lK + c * 2048);
    gload_lds16(gVb + c * 32 * SEQ + kv0,   lV + c * 2048);
  }
}

__device__ __forceinline__ void attn_compute(
    const u16* __restrict__ Kb, const u16* __restrict__ Vb,
    const h16x8 (&qf)[2][2], f32x4 (&O)[2][4], f32x4 (&Lacc)[2],
    h16x8 onesv, int m, int quad)
{
#pragma unroll
  for (int p = 0; p < 2; ++p) {
    const int krow0 = 32 * p + m;
    const int krow1 = krow0 + 16;
    h16x8 kb00 = *(const h16x8*)(Kb + krow0 * 64 + ((    quad) ^ (m & 7)) * 8);
    h16x8 kb01 = *(const h16x8*)(Kb + krow0 * 64 + ((4 + quad) ^ (m & 7)) * 8);
    h16x8 kb10 = *(const h16x8*)(Kb + krow1 * 64 + ((    quad) ^ (m & 7)) * 8);
    h16x8 kb11 = *(const h16x8*)(Kb + krow1 * 64 + ((4 + quad) ^ (m & 7)) * 8);

    h16x8 vb[4];
#pragma unroll
    for (int jd = 0; jd < 4; jd++) {
      int d = jd * 16 + m;
      vb[jd] = *(const h16x8*)(Vb + d * 64 + (((p * 4 + quad) ^ (m & 7)) * 8));
    }

#pragma unroll
    for (int qn = 0; qn < 2; qn++) {
      __builtin_amdgcn_s_setprio(1);
      f32x4 S0 = MFMA32(kb00, qf[qn][0], ZERO4);
      S0       = MFMA32(kb01, qf[qn][1], S0);
      f32x4 S1 = MFMA32(kb10, qf[qn][0], ZERO4);
      S1       = MFMA32(kb11, qf[qn][1], S1);
      __builtin_amdgcn_s_setprio(0);

      float e0 = __builtin_amdgcn_exp2f(S0[0]);
      float e1 = __builtin_amdgcn_exp2f(S0[1]);
      float e2 = __builtin_amdgcn_exp2f(S0[2]);
      float e3 = __builtin_amdgcn_exp2f(S0[3]);
      float e4 = __builtin_amdgcn_exp2f(S1[0]);
      float e5 = __builtin_amdgcn_exp2f(S1[1]);
      float e6 = __builtin_amdgcn_exp2f(S1[2]);
      float e7 = __builtin_amdgcn_exp2f(S1[3]);

      fp16x2 p01 = __builtin_amdgcn_cvt_pkrtz(e0, e1);
      fp16x2 p23 = __builtin_amdgcn_cvt_pkrtz(e2, e3);
      fp16x2 p45 = __builtin_amdgcn_cvt_pkrtz(e4, e5);
      fp16x2 p67 = __builtin_amdgcn_cvt_pkrtz(e6, e7);
      h16x2 q01 = __builtin_bit_cast(h16x2, p01);
      h16x2 q23 = __builtin_bit_cast(h16x2, p23);
      h16x2 q45 = __builtin_bit_cast(h16x2, p45);
      h16x2 q67 = __builtin_bit_cast(h16x2, p67);
      h16x4 pl = __builtin_shufflevector(q01, q23, 0, 1, 2, 3);
      h16x4 ph = __builtin_shufflevector(q45, q67, 0, 1, 2, 3);
      h16x8 pa = __builtin_shufflevector(pl, ph, 0, 1, 2, 3, 4, 5, 6, 7);

      __builtin_amdgcn_s_setprio(1);
#pragma unroll
      for (int jd = 0; jd < 4; jd++)
        O[qn][jd] = MFMA32(pa, vb[jd], O[qn][jd]);
      // row-sum of pa via all-ones B: denominator, replicated over 16 cols.
      Lacc[qn] = MFMA32(pa, onesv, Lacc[qn]);
      __builtin_amdgcn_s_setprio(0);
    }
  }
}

__global__ __launch_bounds__(256, 3) void attn_k(
    const u16* __restrict__ Qh, const u16* __restrict__ Kh, const u16* __restrict__ Vt,
    float* __restrict__ out0, u16* __restrict__ Op1, float* __restrict__ Lp,
    unsigned* __restrict__ flags)
{
  __shared__ u16 Ks[3][64 * 64];  // 3 x 8 KB [kv][d], 16B chunks swizzled ^(kv&7)
  __shared__ u16 Vs[3][64 * 64];  // 3 x 8 KB [d][kv'], kv' pi-permuted per
                                  //   32-group, 16B chunks swizzled ^(d&7)

  const int t = threadIdx.x;
  const int wave = t >> 6, lane = t & 63;
  const int m = lane & 15, quad = lane >> 4;

  // T1 bijective XCD swizzle: 768 blocks = 8 XCDs x 96 (R14-proven: attn
  // FETCH_SIZE 52.3k -> 12.4k KB).
  const int lin = blockIdx.x + 32 * (blockIdx.y + 12 * blockIdx.z);
  const int swz = (lin & 7) * 96 + (lin >> 3);
  const int h  = (swz >> 5) % 12;
  const int q0 = (swz & 31) * 128;
  const int sp = swz / 384;
  const int kvbase = sp * 2048;

  h16x8 qf[2][2];
#pragma unroll
  for (int qn = 0; qn < 2; qn++)
#pragma unroll
    for (int ks = 0; ks < 2; ks++)
      qf[qn][ks] = *(const h16x8*)(Qh + (q0 + wave * 32 + qn * 16 + m) * HID
                                   + h * DH + ks * 32 + quad * 8);

  f32x4 O[2][4];
#pragma unroll
  for (int qn = 0; qn < 2; qn++)
#pragma unroll
    for (int jd = 0; jd < 4; jd++) O[qn][jd] = ZERO4;
  f32x4 Lacc[2] = {ZERO4, ZERO4};

  h16x8 onesv;
#pragma unroll
  for (int j = 0; j < 8; j++) onesv[j] = (_Float16)1.0f;

  const int srow = wave * 8 + (lane >> 3);
  const int swzl = ((lane & 7) ^ (srow & 7)) * 8;
  const u16* gKb = Kh + srow * HID + h * DH + swzl;
  const u16* gVb = Vt + (h * DH + srow) * SEQ + swzl;
  u16* lK0 = &Ks[0][wave * 512]; u16* lV0 = &Vs[0][wave * 512];
  u16* lK1 = &Ks[1][wave * 512]; u16* lV1 = &Vs[1][wave * 512];
  u16* lK2 = &Ks[2][wave * 512]; u16* lV2 = &Vs[2][wave * 512];

  stage_kv(gKb, gVb, lK0, lV0, kvbase);
  stage_kv(gKb, gVb, lK1, lV1, kvbase + 64);

  for (int it = 0; it < 30; it += 3) {
    WAITV(4); SBAR(); SCHED0();
    stage_kv(gKb, gVb, lK2, lV2, kvbase + (it + 2) * 64);
    attn_compute(&Ks[0][0], &Vs[0][0], qf, O, Lacc, onesv, m, quad);
    SCHED0();

    WAITV(4); SBAR(); SCHED0();
    stage_kv(gKb, gVb, lK0, lV0, kvbase + (it + 3) * 64);
    attn_compute(&Ks[1][0], &Vs[1][0], qf, O, Lacc, onesv, m, quad);
    SCHED0();

    WAITV(4); SBAR(); SCHED0();
    stage_kv(gKb, gVb, lK1, lV1, kvbase + (it + 4) * 64);
    attn_compute(&Ks[2][0], &Vs[2][0], qf, O, Lacc, onesv, m, quad);
    SCHED0();
  }
  WAITV(4); SBAR(); SCHED0();
  attn_compute(&Ks[0][0], &Vs[0][0], qf, O, Lacc, onesv, m, quad);
  SCHED0();
  WAITV(0); SBAR(); SCHED0();
  attn_compute(&Ks[1][0], &Vs[1][0], qf, O, Lacc, onesv, m, quad);

  // ======================= partial write =======================
  // sp0 -> full f32 tile into out0; sp1 -> full fp16 tile into Op1.
  // Both write their Lp half (either may finish first).
#pragma unroll
  for (int qn = 0; qn < 2; qn++) {
    if (m == 0) {
#pragma unroll
      for (int r = 0; r < 4; r++)
        Lp[sp * NH * SEQ + h * SEQ + q0 + wave * 32 + qn * 16 + quad * 4 + r] =
            Lacc[qn][r];
    }
#pragma unroll
    for (int jd = 0; jd < 4; jd++) {
      int col = h * DH + jd * 16 + m;
#pragma unroll
      for (int r = 0; r < 4; r++) {
        int row = q0 + wave * 32 + qn * 16 + quad * 4 + r;
        if (sp == 0) out0[row * HID + col] = O[qn][jd][r];
        else         Op1[row * HID + col] = f2h(O[qn][jd][r]);
      }
    }
  }

  // ======================= last-pair-member combine =======================
  // flags[] zeroed EVERY launch by the captured hipMemsetAsync enqueued
  // between qkv and attn. First finisher bumps and exits; second combines.
  __syncthreads();                       // all partial stores drained (vmcnt0)
  unsigned* flagp = flags + (q0 >> 7) * NH + h;
  volatile unsigned* lflag = (volatile unsigned*)&Ks[0][0];   // LDS scratch
  if (t == 0) {
    __threadfence();                     // release: writes visible device-wide
    *lflag = atomicAdd(flagp, 1u);
  }
  __syncthreads();
  if (*lflag == 1u) {
    __threadfence();                     // acquire: invalidate before reads
    const float* LpA = Lp + h * SEQ;               // sp0 denominators
    const float* LpB = Lp + NH * SEQ + h * SEQ;    // sp1 denominators
#pragma unroll
    for (int qn = 0; qn < 2; qn++) {
#pragma unroll
      for (int jd = 0; jd < 4; jd++) {
        int col = h * DH + jd * 16 + m;
#pragma unroll
        for (int r = 0; r < 4; r++) {
          int row = q0 + wave * 32 + qn * 16 + quad * 4 + r;
          float inv = __builtin_amdgcn_rcpf(LpA[row] + LpB[row]);
          float mine = O[qn][jd][r];
          float other = (sp == 0) ? h2f(Op1[row * HID + col])   // partner fp16
                                  : out0[row * HID + col];      // partner f32
          out0[row * HID + col] = (mine + other) * inv;
        }
      }
    }
  }
}

// ---------------------------------------------------------------------------
// Launch. ws layout (bytes) — TOTAL 28,704,768 (R0-proven footprint):
//   Qh [0, 6291456) | Kh [6291456, 12582912) | Vt [12582912, 18874368)
//   xh [18874368, 25165824) | wqh | wkh | wvh [.., 28704768)
//   Op1 (u16) aliases xh; Lp (f32) aliases wqh [25165824, 25559040);
//   flags (384 u32) at [25559040, 25560576) — dead wqh space, zeroed by a
//   captured hipMemsetAsync AFTER qkv (wqh dead by then) on every launch.
// ---------------------------------------------------------------------------
extern "C" void kernel_launch(void* const* d_in, const int* in_sizes, int n_in,
                              void* d_out, int out_size, void* d_ws, size_t ws_size,
                              hipStream_t stream) {
  const float* x  = (const float*)d_in[0];
  const float* Wq = (const float*)d_in[1];
  const float* bq = (const float*)d_in[2];
  const float* Wk = (const float*)d_in[3];
  const float* bk = (const float*)d_in[4];
  const float* Wv = (const float*)d_in[5];
  const float* bv = (const float*)d_in[6];
  float* out = (float*)d_out;

  char* ws = (char*)d_ws;
  u16* Qh  = (u16*)(ws);
  u16* Kh  = (u16*)(ws + 6291456);
  u16* Vt  = (u16*)(ws + 12582912);
  u16* xh  = (u16*)(ws + 18874368);
  u16* wqh = (u16*)(ws + 25165824);
  u16* wkh = (u16*)(ws + 26345472);
  u16* wvh = (u16*)(ws + 27525120);
  u16*      Op1   = (u16*)(ws + 18874368);             // aliases xh
  float*    Lp    = (float*)(ws + 25165824);           // aliases wqh
  unsigned* flags = (unsigned*)(ws + 25559040);        // after Lp, dead wqh

  cast_all_k<<<4800, 256, 0, stream>>>(x, Wq, Wk, Wv, xh, wqh, wkh, wvh);
  qkv_gemm_k<<<dim3(6, 32, 3), 256, 0, stream>>>(xh, wqh, wkh, wvh,
                                                 bq, bk, bv, Qh, Kh, Vt);
  // re-arm combine flags every launch (graph-captured, stream-ordered:
  // wqh bytes are dead after qkv_gemm_k).
  hipMemsetAsync(flags, 0, 384 * sizeof(unsigned), stream);
  attn_k<<<dim3(32, NH, 2), 256, 0, stream>>>(Qh, Kh, Vt, out, Op1, Lp, flags);
}

// Round 11
// 152.979 us; speedup vs baseline: 1.8836x; 1.8836x over previous
//
#include <hip/hip_runtime.h>
#include <stdint.h>

// ---------------------------------------------------------------------------
// RandomizedBertSelfAttention: fused QKV projection + flash attention.
// R20 = R14 verbatim (session best, 156.4us). R19's in-dispatch combine
// regressed 1.8x: device-scope release __threadfence per block forces L2
// writeback of the 12.6MB out0 partials (WRITE_SIZE 18.8->31.2MB) and
// serializes epilogues -- on CDNA4 a kernel boundary is CHEAPER than
// per-block cross-XCD fencing. Fusion avenues (R17 cooperative, R18/R19
// atomic) both empirically closed. Structure: cast -> qkv (R9-proven
// 128x128/BK64 full-drain + XCD swizzle) -> attn (R11 3-ring counted-
// vmcnt + T1 swizzle, ones-MFMA lsum) -> reduce.
// ---------------------------------------------------------------------------

typedef float    f32x4 __attribute__((ext_vector_type(4)));
typedef _Float16 h16x8 __attribute__((ext_vector_type(8)));
typedef _Float16 h16x4 __attribute__((ext_vector_type(4)));
typedef _Float16 h16x2 __attribute__((ext_vector_type(2)));
typedef __fp16   fp16x2 __attribute__((ext_vector_type(2)));
typedef unsigned short u16;

#define MFMA32(A, B, C) __builtin_amdgcn_mfma_f32_16x16x32_f16((A), (B), (C), 0, 0, 0)
#define ZERO4 ((f32x4){0.f, 0.f, 0.f, 0.f})

#define SEQ 4096
#define HID 768
#define NH  12
#define DH  64

#define CEXP 0.18033688011112042f   // log2(e)/sqrt(64), folded into Q

#define WAITV(N) asm volatile("s_waitcnt vmcnt(" #N ")" ::: "memory")
#define SBAR()   __builtin_amdgcn_s_barrier()
#define SCHED0() __builtin_amdgcn_sched_barrier(0)

__device__ __forceinline__ u16 f2h(float f) {
  union { _Float16 h; u16 u; } v;
  v.h = (_Float16)f;
  return v.u;
}
__device__ __forceinline__ float h2f(u16 u) {
  union { u16 u; _Float16 h; } v;
  v.u = u;
  return (float)v.h;
}

__device__ __forceinline__ void gload_lds16(const void* g, void* l) {
  __builtin_amdgcn_global_load_lds(
      (__attribute__((address_space(1))) void*)(g),
      (__attribute__((address_space(3))) void*)(l),
      16, 0, 0);
}

// ---------------------------------------------------------------------------
// Kernel 1: cast x, Wq, Wk, Wv to fp16
// ---------------------------------------------------------------------------
__global__ __launch_bounds__(256) void cast_all_k(
    const float* __restrict__ x,  const float* __restrict__ wq,
    const float* __restrict__ wk, const float* __restrict__ wv,
    u16* __restrict__ xh,  u16* __restrict__ wqh,
    u16* __restrict__ wkh, u16* __restrict__ wvh)
{
  int i = blockIdx.x * 256 + threadIdx.x;
  const int NX4 = (SEQ * HID) / 4;
  const int NW4 = (HID * HID) / 4;
  const float4* src; ushort4* dst; int idx;
  if (i < NX4) {
    src = (const float4*)x; dst = (ushort4*)xh; idx = i;
  } else {
    int j = i - NX4;
    int w = j / NW4;
    idx = j - w * NW4;
    src = (const float4*)(w == 0 ? wq : (w == 1 ? wk : wv));
    dst = (ushort4*)(w == 0 ? wqh : (w == 1 ? wkh : wvh));
  }
  float4 v = src[idx];
  ushort4 o;
  o.x = f2h(v.x); o.y = f2h(v.y); o.z = f2h(v.z); o.w = f2h(v.w);
  dst[idx] = o;
}

// ---------------------------------------------------------------------------
// Kernel 2: QKV projection GEMM, C = x @ W^T + b. 128x128 tile, BK=64,
// XOR-swizzled LDS staging (conflict-free frags), launch_bounds(256,3).
// z==0 (Q): pre-scaled by CEXP. z==2 (V): stored transposed Vt[hid][s] with
// the PV permutation pi per 32-kv group (pi applied at the LDS-transpose
// stage). Epilogue: acc -> swizzled LDS (Cs = As/Bs space, 32 KB) -> b128
// row reads -> coalesced dwordx4 global stores. (R9-proven version.)
// ---------------------------------------------------------------------------
__global__ __launch_bounds__(256, 3) void qkv_gemm_k(
    const u16* __restrict__ xh,
    const u16* __restrict__ wqh, const u16* __restrict__ wkh, const u16* __restrict__ wvh,
    const float* __restrict__ bq, const float* __restrict__ bk, const float* __restrict__ bv,
    u16* __restrict__ Qh, u16* __restrict__ Kh, u16* __restrict__ Vt)
{
  __shared__ u16 S[128 * 128];   // 32 KB: K-loop: A=[0,8192), B=[8192,16384) u16
                                 // epilogue: Cs[128][128] (swizzled chunks)

  const int t = threadIdx.x;
  const int wave = t >> 6, lane = t & 63;
  const int m = lane & 15, quad = lane >> 4;
  const int z  = blockIdx.z;
  const int n0 = blockIdx.x * 128;
  const int m0 = blockIdx.y * 128;

  const u16*   W    = (z == 0) ? wqh : (z == 1) ? wkh : wvh;
  const float* bias = (z == 0) ? bq  : (z == 1) ? bk  : bv;

  const int wm = (wave >> 1) * 64;
  const int wn = (wave & 1) * 64;

  f32x4 acc[4][4];
#pragma unroll
  for (int i = 0; i < 4; i++)
#pragma unroll
    for (int j = 0; j < 4; j++) acc[i][j] = ZERO4;

  // staging: call c covers rows c*32 + wave*8 + (lane>>3), chunk lane&7,
  // global-side swizzle ^(row&7); LDS dest contiguous (wave base + lane*16)
  const int srow = wave * 8 + (lane >> 3);
  const int scg  = (lane & 7) ^ (srow & 7);
  const u16* gA = xh + (m0 + srow) * HID + scg * 8;
  const u16* gB = W  + (n0 + srow) * HID + scg * 8;
  u16* lA = S + wave * 512;
  u16* lB = S + 8192 + wave * 512;

  for (int k0 = 0; k0 < HID; k0 += 64) {
    __syncthreads();
#pragma unroll
    for (int c = 0; c < 4; c++) {
      gload_lds16(gA + c * 32 * HID + k0, lA + c * 2048);
      gload_lds16(gB + c * 32 * HID + k0, lB + c * 2048);
    }
    __syncthreads();

#pragma unroll
    for (int s = 0; s < 2; s++) {
      h16x8 af[4], bf[4];
#pragma unroll
      for (int i = 0; i < 4; i++)
        af[i] = *(const h16x8*)(S + (wm + i * 16 + m) * 64
                                + ((s * 4 + quad) ^ (m & 7)) * 8);
#pragma unroll
      for (int j = 0; j < 4; j++)
        bf[j] = *(const h16x8*)(S + 8192 + (wn + j * 16 + m) * 64
                                + ((s * 4 + quad) ^ (m & 7)) * 8);
#pragma unroll
      for (int i = 0; i < 4; i++)
#pragma unroll
        for (int j = 0; j < 4; j++)
          acc[i][j] = MFMA32(af[i], bf[j], acc[i][j]);
    }
  }

  __syncthreads();   // all frag reads done — S becomes the epilogue tile Cs

  // C/D layout: col = lane&15 (within 16-tile), row = quad*4 + reg
  if (z < 2) {
    // Cs[s][col'] u16, chunk (col'>>3) stored at slot ^(s&15)
    const float sc = (z == 0) ? CEXP : 1.0f;
#pragma unroll
    for (int i = 0; i < 4; i++) {
      int sl = wm + i * 16 + quad * 4;            // local s, +r
#pragma unroll
      for (int j = 0; j < 4; j++) {
        int colp = wn + j * 16 + m;               // local col
        float bb = bias[n0 + colp];
        int c = colp >> 3, sub = colp & 7;
#pragma unroll
        for (int r = 0; r < 4; r++)
          S[(sl + r) * 128 + ((c ^ ((sl + r) & 15)) * 8) + sub] =
              f2h((acc[i][j][r] + bb) * sc);
      }
    }
    __syncthreads();
    u16* outp = (z == 0) ? Qh : Kh;
    const int ch = t & 15;                        // global chunk this thread reads
#pragma unroll
    for (int rr = 0; rr < 8; rr++) {
      int s = rr * 16 + (t >> 4);
      h16x8 v = *(const h16x8*)(S + s * 128 + ((ch ^ (s & 15)) * 8));
      *(h16x8*)(outp + (m0 + s) * HID + n0 + ch * 8) = v;
    }
  } else {
    // Cs[n][s'] u16 with pi-permuted s' (per 32-group); b64 writes (4-phase floor)
#pragma unroll
    for (int i = 0; i < 4; i++) {
      int sl = wm + i * 16 + quad * 4;            // local s, multiple of 4
      int vp = (sl & ~31) + ((sl >> 2) & 3) * 8 + ((sl >> 4) & 1) * 4;
#pragma unroll
      for (int j = 0; j < 4; j++) {
        int nl = wn + j * 16 + m;                 // local hid
        float bb = bias[n0 + nl];
        h16x4 o4;
        o4[0] = (_Float16)(acc[i][j][0] + bb);
        o4[1] = (_Float16)(acc[i][j][1] + bb);
        o4[2] = (_Float16)(acc[i][j][2] + bb);
        o4[3] = (_Float16)(acc[i][j][3] + bb);
        *(h16x4*)(S + nl * 128 + (((vp >> 3) ^ (nl & 15)) * 8) + (vp & 7)) = o4;
      }
    }
    __syncthreads();
    const int ch = t & 15;
#pragma unroll
    for (int rr = 0; rr < 8; rr++) {
      int n = rr * 16 + (t >> 4);
      h16x8 v = *(const h16x8*)(S + n * 128 + ((ch ^ (n & 15)) * 8));
      *(h16x8*)(Vt + (n0 + n) * SEQ + m0 + ch * 8) = v;
    }
  }
}

// ---------------------------------------------------------------------------
// Kernel 3: flash attention, split-KV x2 (R11 structure, 57.8us proven) +
// R14 bijective XCD swizzle. Block = 256 threads (4 waves), 32 q-rows/wave.
// QK^T swapped (A=K, B=Q): S^T C-layout == 16x16x32 A-operand layout under
// pi (baked into Vt), PV register-direct. KVBLK=64, 3-ring Ks/Vs (3x8KB
// each, 48KB), single barrier per tile: WAITV(4) -> s_barrier ->
// stage(t+2) -> compute(t). Row-sums via ones-MFMA into Lacc; setprio
// around MFMA clusters. Grid 768 = 3 blocks/CU, 12 waves/CU. No online max.
// ---------------------------------------------------------------------------

// stage one 64-kv tile (K: [64][64] u16, V: [64][64] u16) into buffer bases
// lK/lV (already offset by wave*512). Per thread: 2 K-loads + 2 V-loads.
__device__ __forceinline__ void stage_kv(const u16* gKb, const u16* gVb,
                                         u16* lK, u16* lV, int kv0)
{
#pragma unroll
  for (int c = 0; c < 2; c++) {
    gload_lds16(gKb + (kv0 + c * 32) * HID, lK + c * 2048);
    gload_lds16(gVb + c * 32 * SEQ + kv0,   lV + c * 2048);
  }
}

__device__ __forceinline__ void attn_compute(
    const u16* __restrict__ Kb, const u16* __restrict__ Vb,
    const h16x8 (&qf)[2][2], f32x4 (&O)[2][4], f32x4 (&Lacc)[2],
    h16x8 onesv, int m, int quad)
{
#pragma unroll
  for (int p = 0; p < 2; ++p) {
    const int krow0 = 32 * p + m;
    const int krow1 = krow0 + 16;
    h16x8 kb00 = *(const h16x8*)(Kb + krow0 * 64 + ((    quad) ^ (m & 7)) * 8);
    h16x8 kb01 = *(const h16x8*)(Kb + krow0 * 64 + ((4 + quad) ^ (m & 7)) * 8);
    h16x8 kb10 = *(const h16x8*)(Kb + krow1 * 64 + ((    quad) ^ (m & 7)) * 8);
    h16x8 kb11 = *(const h16x8*)(Kb + krow1 * 64 + ((4 + quad) ^ (m & 7)) * 8);

    h16x8 vb[4];
#pragma unroll
    for (int jd = 0; jd < 4; jd++) {
      int d = jd * 16 + m;
      vb[jd] = *(const h16x8*)(Vb + d * 64 + (((p * 4 + quad) ^ (m & 7)) * 8));
    }

#pragma unroll
    for (int qn = 0; qn < 2; qn++) {
      __builtin_amdgcn_s_setprio(1);
      f32x4 S0 = MFMA32(kb00, qf[qn][0], ZERO4);
      S0       = MFMA32(kb01, qf[qn][1], S0);
      f32x4 S1 = MFMA32(kb10, qf[qn][0], ZERO4);
      S1       = MFMA32(kb11, qf[qn][1], S1);
      __builtin_amdgcn_s_setprio(0);

      float e0 = __builtin_amdgcn_exp2f(S0[0]);
      float e1 = __builtin_amdgcn_exp2f(S0[1]);
      float e2 = __builtin_amdgcn_exp2f(S0[2]);
      float e3 = __builtin_amdgcn_exp2f(S0[3]);
      float e4 = __builtin_amdgcn_exp2f(S1[0]);
      float e5 = __builtin_amdgcn_exp2f(S1[1]);
      float e6 = __builtin_amdgcn_exp2f(S1[2]);
      float e7 = __builtin_amdgcn_exp2f(S1[3]);

      fp16x2 p01 = __builtin_amdgcn_cvt_pkrtz(e0, e1);
      fp16x2 p23 = __builtin_amdgcn_cvt_pkrtz(e2, e3);
      fp16x2 p45 = __builtin_amdgcn_cvt_pkrtz(e4, e5);
      fp16x2 p67 = __builtin_amdgcn_cvt_pkrtz(e6, e7);
      h16x2 q01 = __builtin_bit_cast(h16x2, p01);
      h16x2 q23 = __builtin_bit_cast(h16x2, p23);
      h16x2 q45 = __builtin_bit_cast(h16x2, p45);
      h16x2 q67 = __builtin_bit_cast(h16x2, p67);
      h16x4 pl = __builtin_shufflevector(q01, q23, 0, 1, 2, 3);
      h16x4 ph = __builtin_shufflevector(q45, q67, 0, 1, 2, 3);
      h16x8 pa = __builtin_shufflevector(pl, ph, 0, 1, 2, 3, 4, 5, 6, 7);

      __builtin_amdgcn_s_setprio(1);
#pragma unroll
      for (int jd = 0; jd < 4; jd++)
        O[qn][jd] = MFMA32(pa, vb[jd], O[qn][jd]);
      // row-sum of pa over this 32-kv chunk via all-ones B: C[q][*] = sum,
      // replicated across all 16 columns; accumulates denominator in Lacc.
      Lacc[qn] = MFMA32(pa, onesv, Lacc[qn]);
      __builtin_amdgcn_s_setprio(0);
    }
  }
}

__global__ __launch_bounds__(256, 3) void attn_k(
    const u16* __restrict__ Qh, const u16* __restrict__ Kh, const u16* __restrict__ Vt,
    float* __restrict__ out0, u16* __restrict__ Op1, float* __restrict__ Lp)
{
  __shared__ u16 Ks[3][64 * 64];  // 3 x 8 KB [kv][d], 16B chunks swizzled ^(kv&7)
  __shared__ u16 Vs[3][64 * 64];  // 3 x 8 KB [d][kv'], kv' pi-permuted per
                                  //   32-group, 16B chunks swizzled ^(d&7)

  const int t = threadIdx.x;
  const int wave = t >> 6, lane = t & 63;
  const int m = lane & 15, quad = lane >> 4;

  // T1 bijective XCD swizzle: 768 blocks = 8 XCDs x 96. Hardware round-
  // robins consecutive linear ids across XCDs; after remap, XCD k serves
  // original ids [k*96,(k+1)*96) = 3 full (h,sp) K/V panels (~3MB < 4MB L2)
  // instead of all 24 panels thrashing every L2.
  const int lin = blockIdx.x + 32 * (blockIdx.y + 12 * blockIdx.z);
  const int swz = (lin & 7) * 96 + (lin >> 3);
  const int h  = (swz >> 5) % 12;
  const int q0 = (swz & 31) * 128;
  const int sp = swz / 384;
  const int kvbase = sp * 2048;

  h16x8 qf[2][2];
#pragma unroll
  for (int qn = 0; qn < 2; qn++)
#pragma unroll
    for (int ks = 0; ks < 2; ks++)
      qf[qn][ks] = *(const h16x8*)(Qh + (q0 + wave * 32 + qn * 16 + m) * HID
                                   + h * DH + ks * 32 + quad * 8);

  f32x4 O[2][4];
#pragma unroll
  for (int qn = 0; qn < 2; qn++)
#pragma unroll
    for (int jd = 0; jd < 4; jd++) O[qn][jd] = ZERO4;
  f32x4 Lacc[2] = {ZERO4, ZERO4};

  h16x8 onesv;
#pragma unroll
  for (int j = 0; j < 8; j++) onesv[j] = (_Float16)1.0f;

  // staging geometry: per call c in {0,1} covers rows c*32 + wave*8 +
  // (lane>>3), chunk lane&7, global-side swizzle ^(row&7); LDS dest linear
  // (wave base + lane*16). Same swizzle for K (row=kv) and V (row=d).
  const int srow = wave * 8 + (lane >> 3);
  const int swzl = ((lane & 7) ^ (srow & 7)) * 8;
  const u16* gKb = Kh + srow * HID + h * DH + swzl;
  const u16* gVb = Vt + (h * DH + srow) * SEQ + swzl;
  u16* lK0 = &Ks[0][wave * 512]; u16* lV0 = &Vs[0][wave * 512];
  u16* lK1 = &Ks[1][wave * 512]; u16* lV1 = &Vs[1][wave * 512];
  u16* lK2 = &Ks[2][wave * 512]; u16* lV2 = &Vs[2][wave * 512];

  // prologue: slots 0,1 <- tiles 0,1 (8 loads in flight)
  stage_kv(gKb, gVb, lK0, lV0, kvbase);
  stage_kv(gKb, gVb, lK1, lV1, kvbase + 64);

  // steady state, 3 tiles per unroll. Per tile: WAITV(4) [own tile-t loads
  // landed, BEFORE barrier => cross-wave visible] -> s_barrier [all waves
  // done computing tile t-1 => slot (t+2)%3 free] -> stage(t+2) ->
  // compute(t). Outstanding vm loads: 8 at WAITV, 8 after stage.
  for (int it = 0; it < 30; it += 3) {
    WAITV(4); SBAR(); SCHED0();
    stage_kv(gKb, gVb, lK2, lV2, kvbase + (it + 2) * 64);
    attn_compute(&Ks[0][0], &Vs[0][0], qf, O, Lacc, onesv, m, quad);
    SCHED0();

    WAITV(4); SBAR(); SCHED0();
    stage_kv(gKb, gVb, lK0, lV0, kvbase + (it + 3) * 64);
    attn_compute(&Ks[1][0], &Vs[1][0], qf, O, Lacc, onesv, m, quad);
    SCHED0();

    WAITV(4); SBAR(); SCHED0();
    stage_kv(gKb, gVb, lK1, lV1, kvbase + (it + 4) * 64);
    attn_compute(&Ks[2][0], &Vs[2][0], qf, O, Lacc, onesv, m, quad);
    SCHED0();
  }
  // tail: tiles 30 (slot 0) and 31 (slot 1), no more staging
  WAITV(4); SBAR(); SCHED0();
  attn_compute(&Ks[0][0], &Vs[0][0], qf, O, Lacc, onesv, m, quad);
  SCHED0();
  WAITV(0); SBAR(); SCHED0();
  attn_compute(&Ks[1][0], &Vs[1][0], qf, O, Lacc, onesv, m, quad);

#pragma unroll
  for (int qn = 0; qn < 2; qn++) {
    // Lacc[qn][r] = denominator for q-row (qn*16 + quad*4 + r), replicated
    // across the 16 m-lanes — write from m==0.
    if (m == 0) {
#pragma unroll
      for (int r = 0; r < 4; r++)
        Lp[sp * NH * SEQ + h * SEQ + q0 + wave * 32 + qn * 16 + quad * 4 + r] =
            Lacc[qn][r];
    }
#pragma unroll
    for (int jd = 0; jd < 4; jd++) {
      int col = h * DH + jd * 16 + m;
#pragma unroll
      for (int r = 0; r < 4; r++) {
        int row = q0 + wave * 32 + qn * 16 + quad * 4 + r;
        if (sp == 0) out0[row * HID + col] = O[qn][jd][r];
        else         Op1[row * HID + col] = f2h(O[qn][jd][r]);
      }
    }
  }
}

// ---------------------------------------------------------------------------
// Kernel 4: combine split-KV partials in place: out = (out + Op1) / (L0+L1)
// ---------------------------------------------------------------------------
__global__ __launch_bounds__(256) void reduce_k(
    float* __restrict__ out, const u16* __restrict__ Op1,
    const float* __restrict__ Lp)
{
  int i = blockIdx.x * 256 + threadIdx.x;
  int s  = i / 192;
  int c4 = i - s * 192;
  int h  = c4 >> 4;
  float L = Lp[h * SEQ + s] + Lp[NH * SEQ + h * SEQ + s];
  float inv = __builtin_amdgcn_rcpf(L);
  float4 a = ((const float4*)out)[i];
  ushort4 b = ((const ushort4*)Op1)[i];
  float4 r;
  r.x = (a.x + h2f(b.x)) * inv;
  r.y = (a.y + h2f(b.y)) * inv;
  r.z = (a.z + h2f(b.z)) * inv;
  r.w = (a.w + h2f(b.w)) * inv;
  ((float4*)out)[i] = r;
}

// ---------------------------------------------------------------------------
// Launch. ws layout (bytes) — TOTAL 28,704,768 (R0-proven footprint):
//   Qh [0, 6291456) | Kh [6291456, 12582912) | Vt [12582912, 18874368)
//   xh [18874368, 25165824) | wqh | wkh | wvh [.., 28704768)
//   Op1 (u16) aliases xh; Lp (f32) aliases wqh — both dead after qkv.
// ---------------------------------------------------------------------------
extern "C" void kernel_launch(void* const* d_in, const int* in_sizes, int n_in,
                              void* d_out, int out_size, void* d_ws, size_t ws_size,
                              hipStream_t stream) {
  const float* x  = (const float*)d_in[0];
  const float* Wq = (const float*)d_in[1];
  const float* bq = (const float*)d_in[2];
  const float* Wk = (const float*)d_in[3];
  const float* bk = (const float*)d_in[4];
  const float* Wv = (const float*)d_in[5];
  const float* bv = (const float*)d_in[6];
  float* out = (float*)d_out;

  char* ws = (char*)d_ws;
  u16* Qh  = (u16*)(ws);
  u16* Kh  = (u16*)(ws + 6291456);
  u16* Vt  = (u16*)(ws + 12582912);
  u16* xh  = (u16*)(ws + 18874368);
  u16* wqh = (u16*)(ws + 25165824);
  u16* wkh = (u16*)(ws + 26345472);
  u16* wvh = (u16*)(ws + 27525120);
  u16*   Op1 = (u16*)(ws + 18874368);    // aliases xh (dead after qkv)
  float* Lp  = (float*)(ws + 25165824);  // aliases wqh (dead after qkv)

  cast_all_k<<<4800, 256, 0, stream>>>(x, Wq, Wk, Wv, xh, wqh, wkh, wvh);
  qkv_gemm_k<<<dim3(6, 32, 3), 256, 0, stream>>>(xh, wqh, wkh, wvh,
                                                 bq, bk, bv, Qh, Kh, Vt);
  attn_k<<<dim3(32, NH, 2), 256, 0, stream>>>(Qh, Kh, Vt, out, Op1, Lp);
  reduce_k<<<3072, 256, 0, stream>>>(out, Op1, Lp);
}